// Round 10
// baseline (746.932 us; speedup 1.0000x reference)
//
#include <hip/hip_runtime.h>
#include <hip/hip_bf16.h>
#include <math.h>

typedef float f32x4 __attribute__((ext_vector_type(4)));
typedef __bf16 bf16x8 __attribute__((ext_vector_type(8)));

#define NTOK 98
#define NWIN 2048
#define NN (NTOK * NTOK)            // 9604
#define SCALE 0.17677669529663689f
#define MROWS (NWIN * NTOK)         // 200704
#define PSTRIDE 10368               // per-(win,h): q 3136 + k 3136 + vT 4096 elems

// ---------------- async global->LDS 16B ----------------
__device__ __forceinline__ void g2l16(const void* g, void* l) {
  typedef __attribute__((address_space(1))) const unsigned int GU;
  typedef __attribute__((address_space(3))) unsigned int LU;
  __builtin_amdgcn_global_load_lds((GU*)g, (LU*)l, 16, 0, 0);
}

// ---------------- prep: weights->bf16, cmb[m][h][98][128] = bias+mask (fp32) ----------------
__global__ void prep_kernel(const float* __restrict__ qkv_w, const float* __restrict__ proj_w,
                            const float* __restrict__ pbt, const int* __restrict__ rpi,
                            const float* __restrict__ mask,
                            __bf16* __restrict__ qkvw_b, __bf16* __restrict__ projw_b,
                            float* __restrict__ cmb) {
  int i = blockIdx.x * 256 + threadIdx.x;
  if (i < 768 * 256) qkvw_b[i] = (__bf16)qkv_w[i];
  if (i < 256 * 256) projw_b[i] = (__bf16)proj_w[i];
  if (i < 256 * 8 * NTOK * 128) {
    int mh = i / (NTOK * 128);            // m*8 + h
    int rem = i - mh * (NTOK * 128);
    int row = rem >> 7, j = rem & 127;
    if (j < NTOK) {
      int m = mh >> 3, h = mh & 7;
      cmb[i] = pbt[rpi[row * NTOK + j] * 8 + h] + mask[m * NN + row * NTOK + j];
    } else {
      cmb[i] = 0.f;
    }
  }
}

// ---------------- zpad: zero V^T pad columns (tok 96..127; gemm refills 96,97) ----------------
__global__ void zpad_kernel(__bf16* __restrict__ qkv) {
  int idx = blockIdx.x * 256 + threadIdx.x;     // 16384*32*4 = 2,097,152
  int wh = idx >> 7;
  int r2 = idx & 127;
  int d = r2 >> 2, c = r2 & 3;
  bf16x8 z = {};
  *(bf16x8*)(qkv + (size_t)wh * PSTRIDE + 6272 + d * 128 + 96 + c * 8) = z;
}

// ---------------- xcast: x fp32 -> bf16 ----------------
__global__ void xcast_kernel(const float* __restrict__ x, __bf16* __restrict__ xb) {
  int i = blockIdx.x * 256 + threadIdx.x;
  const float* p = x + (size_t)i * 8;
  float4 f0 = *(const float4*)p;
  float4 f1 = *(const float4*)(p + 4);
  bf16x8 hv;
  hv[0] = (__bf16)f0.x; hv[1] = (__bf16)f0.y; hv[2] = (__bf16)f0.z; hv[3] = (__bf16)f0.w;
  hv[4] = (__bf16)f1.x; hv[5] = (__bf16)f1.y; hv[6] = (__bf16)f1.z; hv[7] = (__bf16)f1.w;
  *(bf16x8*)(xb + (size_t)i * 8) = hv;
}

// ---------------- QKV GEMM: xb @ W^T -> qkv {q[98][32], k[98][32], vT[32][128]} ----------------
__launch_bounds__(256)
__global__ void gemm_qkv(const __bf16* __restrict__ A, const __bf16* __restrict__ W,
                         __bf16* __restrict__ C) {
  __shared__ __align__(16) char As[128 * 128];
  __shared__ __align__(16) char Bs[128 * 128];
  // XCD chunking: 9408 blocks, 1176/XCD; consecutive lb (sharing A panel) on same XCD
  const int bx = blockIdx.x;
  const int lb = (bx & 7) * 1176 + (bx >> 3);
  const int m0 = (lb / 6) * 128;
  const int n0 = (lb % 6) * 128;
  const int tid = threadIdx.x;
  const int lane = tid & 63;
  const int wid = tid >> 6;
  const int wm = wid & 1, wn = wid >> 1;
  const int lr = lane & 15;
  const int lg = lane >> 4;
  f32x4 acc[4][4] = {};

  for (int k0 = 0; k0 < 256; k0 += 64) {
#pragma unroll
    for (int it = 0; it < 4; ++it) {
      int c = wid * 4 + it;
      int row = c * 8 + (lane >> 3);
      int src_chunk = (lane & 7) ^ (row & 7);
      g2l16(A + (size_t)(m0 + row) * 256 + k0 + src_chunk * 8, (void*)(As + c * 1024));
      g2l16(W + (size_t)(n0 + row) * 256 + k0 + src_chunk * 8, (void*)(Bs + c * 1024));
    }
    __syncthreads();
#pragma unroll
    for (int kk = 0; kk < 2; ++kk) {
      bf16x8 a[4], b[4];
#pragma unroll
      for (int m = 0; m < 4; ++m) {
        int row = wm * 64 + m * 16 + lr;
        a[m] = *(const bf16x8*)(As + row * 128 + ((kk * 64 + lg * 16) ^ ((row & 7) << 4)));
      }
#pragma unroll
      for (int n = 0; n < 4; ++n) {
        int row = wn * 64 + n * 16 + lr;
        b[n] = *(const bf16x8*)(Bs + row * 128 + ((kk * 64 + lg * 16) ^ ((row & 7) << 4)));
      }
#pragma unroll
      for (int m = 0; m < 4; ++m)
#pragma unroll
        for (int n = 0; n < 4; ++n)
          acc[m][n] = __builtin_amdgcn_mfma_f32_16x16x32_bf16(a[m], b[n], acc[m][n], 0, 0, 0);
    }
    __syncthreads();
  }
  // epilogue: head-blocked scatter; V stored transposed [32 d][128 tok]
#pragma unroll
  for (int m = 0; m < 4; ++m)
#pragma unroll
    for (int r = 0; r < 4; ++r) {
      unsigned row = m0 + wm * 64 + m * 16 + lg * 4 + r;
      unsigned win = row / NTOK;
      unsigned tok = row - win * NTOK;
#pragma unroll
      for (int n = 0; n < 4; ++n) {
        int col = n0 + wn * 64 + n * 16 + lr;
        int sec = col >> 8, dd = col & 255;
        int h = dd >> 5, d = dd & 31;
        size_t base = (size_t)(win * 8 + h) * PSTRIDE;
        size_t off = (sec < 2) ? base + (size_t)sec * 3136 + tok * 32 + d
                               : base + 6272 + d * 128 + tok;
        C[off] = (__bf16)acc[m][n][r];
      }
    }
}

// ---------------- attention: zero-LDS, zero-barrier; block=(m,h,rep), 2 waves ----------------
__launch_bounds__(128)
__global__ void attn_kernel(const __bf16* __restrict__ qkv, const float* __restrict__ cmb,
                            __bf16* __restrict__ y) {
  int bx = blockIdx.x;
  // mask-locality XCD mapping: xcd=bx&7 owns cmb slices m in [xcd*32, xcd*32+32);
  // rep (8 windows sharing a slice) innermost -> slice stays in that XCD's L2.
  int xcd = bx & 7, seq = bx >> 3;
  int m = xcd * 32 + (seq >> 6);
  int rem = seq & 63;
  int h = rem >> 3, rep = rem & 7;
  int win = m + (rep << 8);

  const int tid = threadIdx.x;
  const int lane = tid & 63, wv = tid >> 6;
  const int lr = lane & 15, lg = lane >> 4;
  const f32x4 fz = {0.f, 0.f, 0.f, 0.f};

  const __bf16* qw = qkv + (size_t)(win * 8 + h) * PSTRIDE;
  const __bf16* kw = qw + 3136;
  const __bf16* vwT = qw + 6272;                 // [32 d][128 tok]
  const float* cw = cmb + (size_t)(m * 8 + h) * (NTOK * 128);

#pragma unroll
  for (int t = 0; t < 4; ++t) {
    const int it = wv * 4 + t;                   // wave0: 0..3, wave1: 4..6(+skip)
    if (it >= 7) continue;
    const int i0 = it * 16;
    const int qrow = i0 + lr;
    const int qrowc = qrow < NTOK ? qrow : NTOK - 1;
    bf16x8 aq = *(const bf16x8*)(qw + qrowc * 32 + lg * 8);

    // S^T = K Q^T, permuted K-row feed: lane holds P[qrow][k], k=32*(jt>>1)+lg*8+4*(jt&1)+r
    f32x4 s[7];
#pragma unroll
    for (int jt = 0; jt < 7; ++jt) {
      int brow = ((jt >> 1) << 5) + ((lr >> 2) << 3) + ((jt & 1) << 2) + (lr & 3);
      int browc = brow < NTOK ? brow : NTOK - 1;
      bf16x8 bk = *(const bf16x8*)(kw + browc * 32 + lg * 8);
      s[jt] = __builtin_amdgcn_mfma_f32_16x16x32_bf16(bk, aq, fz, 0, 0, 0);
    }

    // softmax fully in-register; combined bias+mask: one float4 per 4 scores
    const float* cr = cw + qrowc * 128;
    float sv[7][4];
    float mx = -INFINITY;
#pragma unroll
    for (int jt = 0; jt < 7; ++jt) {
      int kb = ((jt >> 1) << 5) + lg * 8 + ((jt & 1) << 2);
      float4 cv = *(const float4*)(cr + kb);
#pragma unroll
      for (int r = 0; r < 4; ++r) {
        float xv = (kb + r < NTOK) ? fmaf(SCALE, s[jt][r], (&cv.x)[r]) : -INFINITY;
        sv[jt][r] = xv;
        mx = fmaxf(mx, xv);
      }
    }
    mx = fmaxf(mx, __shfl_xor(mx, 16));
    mx = fmaxf(mx, __shfl_xor(mx, 32));
    float sum = 0.f;
#pragma unroll
    for (int jt = 0; jt < 7; ++jt)
#pragma unroll
      for (int r = 0; r < 4; ++r) {
        float p = __expf(sv[jt][r] - mx);
        sv[jt][r] = p;
        sum += p;
      }
    sum += __shfl_xor(sum, 16);
    sum += __shfl_xor(sum, 32);
    const float rinv = 1.f / sum;

    // PV A-frags (slots match held P layout); jt==7 phantom slots -> 0
    bf16x8 pa[4];
#pragma unroll
    for (int ks = 0; ks < 4; ++ks)
#pragma unroll
      for (int e = 0; e < 8; ++e) {
        int jt = 2 * ks + (e >> 2);
        pa[ks][e] = (jt < 7) ? (__bf16)(sv[jt][e & 3] * rinv) : (__bf16)0.f;
      }

    // PV: B-frags direct from global V^T (coalesced bf16x8)
#pragma unroll
    for (int dt = 0; dt < 2; ++dt) {
      f32x4 o = fz;
#pragma unroll
      for (int ks = 0; ks < 4; ++ks) {
        int vrow = dt * 16 + lr;
        bf16x8 vb = *(const bf16x8*)(vwT + vrow * 128 + ks * 32 + lg * 8);
        o = __builtin_amdgcn_mfma_f32_16x16x32_bf16(pa[ks], vb, o, 0, 0, 0);
      }
#pragma unroll
      for (int r = 0; r < 4; ++r) {
        int row = i0 + lg * 4 + r;
        if (row < NTOK)
          y[((size_t)win * NTOK + row) * 256 + h * 32 + dt * 16 + lr] = (__bf16)o[r];
      }
    }
  }
}

// ---------------- proj GEMM: out[M][256] = y[M][256] @ W[256][256]^T + b ----------------
__launch_bounds__(256)
__global__ void gemm_proj(const __bf16* __restrict__ A, const __bf16* __restrict__ W,
                          const float* __restrict__ pb, float* __restrict__ C) {
  __shared__ __align__(16) char As[128 * 128];
  __shared__ __align__(16) char Bs[128 * 128];
  // XCD chunking: 3136 blocks, 392/XCD
  const int bx = blockIdx.x;
  const int lb = (bx & 7) * 392 + (bx >> 3);
  const int m0 = (lb / 2) * 128;
  const int n0 = (lb % 2) * 128;
  const int tid = threadIdx.x;
  const int lane = tid & 63;
  const int wid = tid >> 6;
  const int wm = wid & 1, wn = wid >> 1;
  const int lr = lane & 15;
  const int lg = lane >> 4;
  f32x4 acc[4][4] = {};

  for (int k0 = 0; k0 < 256; k0 += 64) {
#pragma unroll
    for (int it = 0; it < 4; ++it) {
      int c = wid * 4 + it;
      int row = c * 8 + (lane >> 3);
      int src_chunk = (lane & 7) ^ (row & 7);
      g2l16(A + (size_t)(m0 + row) * 256 + k0 + src_chunk * 8, (void*)(As + c * 1024));
      g2l16(W + (size_t)(n0 + row) * 256 + k0 + src_chunk * 8, (void*)(Bs + c * 1024));
    }
    __syncthreads();
#pragma unroll
    for (int kk = 0; kk < 2; ++kk) {
      bf16x8 a[4], b[4];
#pragma unroll
      for (int m = 0; m < 4; ++m) {
        int row = wm * 64 + m * 16 + lr;
        a[m] = *(const bf16x8*)(As + row * 128 + ((kk * 64 + lg * 16) ^ ((row & 7) << 4)));
      }
#pragma unroll
      for (int n = 0; n < 4; ++n) {
        int row = wn * 64 + n * 16 + lr;
        b[n] = *(const bf16x8*)(Bs + row * 128 + ((kk * 64 + lg * 16) ^ ((row & 7) << 4)));
      }
#pragma unroll
      for (int m = 0; m < 4; ++m)
#pragma unroll
        for (int n = 0; n < 4; ++n)
          acc[m][n] = __builtin_amdgcn_mfma_f32_16x16x32_bf16(a[m], b[n], acc[m][n], 0, 0, 0);
    }
    __syncthreads();
  }
#pragma unroll
  for (int m = 0; m < 4; ++m) {
    int row = m0 + wm * 64 + m * 16 + lg * 4;
#pragma unroll
    for (int n = 0; n < 4; ++n) {
      int col = n0 + wn * 64 + n * 16 + lr;
      float bv = pb[col];
#pragma unroll
      for (int r = 0; r < 4; ++r)
        C[(size_t)(row + r) * 256 + col] = acc[m][n][r] + bv;
    }
  }
}

// ---------------- launch ----------------
extern "C" void kernel_launch(void* const* d_in, const int* in_sizes, int n_in,
                              void* d_out, int out_size, void* d_ws, size_t ws_size,
                              hipStream_t stream) {
  const float* x      = (const float*)d_in[0];
  const float* mask   = (const float*)d_in[1];
  const float* pbt    = (const float*)d_in[2];
  const float* qkv_w  = (const float*)d_in[3];
  const float* proj_w = (const float*)d_in[4];
  const float* proj_b = (const float*)d_in[5];
  const int*   rpi    = (const int*)d_in[6];
  float* out = (float*)d_out;

  char* ws = (char*)d_ws;
  __bf16* qkv      = (__bf16*)(ws);                   // 16384*10368*2 = 339,738,624
  __bf16* xb       = (__bf16*)(ws + 339738624);       // 103MB; ALIASES y (xb dead before attn)
  __bf16* y        = (__bf16*)(ws + 339738624);       // 200704*256*2 = 102,760,448
  __bf16* qkvw_b   = (__bf16*)(ws + 442499072);       // 393,216
  __bf16* projw_b  = (__bf16*)(ws + 442892288);       // 131,072
  float*  cmb      = (float*) (ws + 443023360);       // 256*8*98*128*4 = 102,760,448 (~546MB)

  int prep_n = 256 * 8 * NTOK * 128;
  prep_kernel<<<(prep_n + 255) / 256, 256, 0, stream>>>(qkv_w, proj_w, pbt, rpi, mask,
                                                        qkvw_b, projw_b, cmb);
  zpad_kernel<<<8192, 256, 0, stream>>>(qkv);
  xcast_kernel<<<MROWS * 256 / 8 / 256, 256, 0, stream>>>(x, xb);
  gemm_qkv<<<(MROWS / 128) * 6, 256, 0, stream>>>(xb, qkvw_b, qkv);
  attn_kernel<<<NWIN * 8, 128, 0, stream>>>(qkv, cmb, y);
  gemm_proj<<<(MROWS / 128) * 2, 256, 0, stream>>>(y, projw_b, proj_b, out);
}

// Round 12
// 645.463 us; speedup vs baseline: 1.1572x; 1.1572x over previous
//
#include <hip/hip_runtime.h>
#include <hip/hip_bf16.h>
#include <math.h>

typedef float f32x4 __attribute__((ext_vector_type(4)));
typedef __bf16 bf16x8 __attribute__((ext_vector_type(8)));

#define NTOK 98
#define NWIN 2048
#define NN (NTOK * NTOK)            // 9604
#define SCALE 0.17677669529663689f
#define MROWS (NWIN * NTOK)         // 200704
#define PSTRIDE 10368               // per-(win,h): q 3136 + k 3136 + vT 4096 elems

// ---------------- async global->LDS 16B ----------------
__device__ __forceinline__ void g2l16(const void* g, void* l) {
  typedef __attribute__((address_space(1))) const unsigned int GU;
  typedef __attribute__((address_space(3))) unsigned int LU;
  __builtin_amdgcn_global_load_lds((GU*)g, (LU*)l, 16, 0, 0);
}

// ---------------- prep: weights->bf16, cmb[m][h][98][128] = bias+mask (fp32) ----------------
__global__ void prep_kernel(const float* __restrict__ qkv_w, const float* __restrict__ proj_w,
                            const float* __restrict__ pbt, const int* __restrict__ rpi,
                            const float* __restrict__ mask,
                            __bf16* __restrict__ qkvw_b, __bf16* __restrict__ projw_b,
                            float* __restrict__ cmb) {
  int i = blockIdx.x * 256 + threadIdx.x;
  if (i < 768 * 256) qkvw_b[i] = (__bf16)qkv_w[i];
  if (i < 256 * 256) projw_b[i] = (__bf16)proj_w[i];
  if (i < 256 * 8 * NTOK * 128) {
    int mh = i / (NTOK * 128);            // m*8 + h
    int rem = i - mh * (NTOK * 128);
    int row = rem >> 7, j = rem & 127;
    if (j < NTOK) {
      int m = mh >> 3, h = mh & 7;
      cmb[i] = pbt[rpi[row * NTOK + j] * 8 + h] + mask[m * NN + row * NTOK + j];
    } else {
      cmb[i] = 0.f;
    }
  }
}

// ---------------- zpad: zero V^T pad columns (tok 96..127; gemm refills 96,97) ----------------
__global__ void zpad_kernel(__bf16* __restrict__ qkv) {
  int idx = blockIdx.x * 256 + threadIdx.x;     // 16384*32*4 = 2,097,152
  int wh = idx >> 7;
  int r2 = idx & 127;
  int d = r2 >> 2, c = r2 & 3;
  bf16x8 z = {};
  *(bf16x8*)(qkv + (size_t)wh * PSTRIDE + 6272 + d * 128 + 96 + c * 8) = z;
}

// ---------------- xcast: x fp32 -> bf16 ----------------
__global__ void xcast_kernel(const float* __restrict__ x, __bf16* __restrict__ xb) {
  int i = blockIdx.x * 256 + threadIdx.x;
  const float* p = x + (size_t)i * 8;
  float4 f0 = *(const float4*)p;
  float4 f1 = *(const float4*)(p + 4);
  bf16x8 hv;
  hv[0] = (__bf16)f0.x; hv[1] = (__bf16)f0.y; hv[2] = (__bf16)f0.z; hv[3] = (__bf16)f0.w;
  hv[4] = (__bf16)f1.x; hv[5] = (__bf16)f1.y; hv[6] = (__bf16)f1.z; hv[7] = (__bf16)f1.w;
  *(bf16x8*)(xb + (size_t)i * 8) = hv;
}

// ---------------- QKV GEMM: xb @ W^T -> qkv {q[98][32], k[98][32], vT[32][128]} ----------------
__launch_bounds__(256)
__global__ void gemm_qkv(const __bf16* __restrict__ A, const __bf16* __restrict__ W,
                         __bf16* __restrict__ C) {
  __shared__ __align__(16) char As[128 * 128];
  __shared__ __align__(16) char Bs[128 * 128];
  const int bid = blockIdx.x;
  const int m0 = (bid / 6) * 128;
  const int n0 = (bid % 6) * 128;
  const int tid = threadIdx.x;
  const int lane = tid & 63;
  const int wid = tid >> 6;
  const int wm = wid & 1, wn = wid >> 1;
  const int lr = lane & 15;
  const int lg = lane >> 4;
  f32x4 acc[4][4] = {};

  for (int k0 = 0; k0 < 256; k0 += 64) {
#pragma unroll
    for (int it = 0; it < 4; ++it) {
      int c = wid * 4 + it;
      int row = c * 8 + (lane >> 3);
      int src_chunk = (lane & 7) ^ (row & 7);
      g2l16(A + (size_t)(m0 + row) * 256 + k0 + src_chunk * 8, (void*)(As + c * 1024));
      g2l16(W + (size_t)(n0 + row) * 256 + k0 + src_chunk * 8, (void*)(Bs + c * 1024));
    }
    __syncthreads();
#pragma unroll
    for (int kk = 0; kk < 2; ++kk) {
      bf16x8 a[4], b[4];
#pragma unroll
      for (int m = 0; m < 4; ++m) {
        int row = wm * 64 + m * 16 + lr;
        a[m] = *(const bf16x8*)(As + row * 128 + ((kk * 64 + lg * 16) ^ ((row & 7) << 4)));
      }
#pragma unroll
      for (int n = 0; n < 4; ++n) {
        int row = wn * 64 + n * 16 + lr;
        b[n] = *(const bf16x8*)(Bs + row * 128 + ((kk * 64 + lg * 16) ^ ((row & 7) << 4)));
      }
#pragma unroll
      for (int m = 0; m < 4; ++m)
#pragma unroll
        for (int n = 0; n < 4; ++n)
          acc[m][n] = __builtin_amdgcn_mfma_f32_16x16x32_bf16(a[m], b[n], acc[m][n], 0, 0, 0);
    }
    __syncthreads();
  }
  // epilogue: head-blocked scatter; V stored transposed [32 d][128 tok]
#pragma unroll
  for (int m = 0; m < 4; ++m)
#pragma unroll
    for (int r = 0; r < 4; ++r) {
      unsigned row = m0 + wm * 64 + m * 16 + lg * 4 + r;
      unsigned win = row / NTOK;
      unsigned tok = row - win * NTOK;
#pragma unroll
      for (int n = 0; n < 4; ++n) {
        int col = n0 + wn * 64 + n * 16 + lr;
        int sec = col >> 8, dd = col & 255;
        int h = dd >> 5, d = dd & 31;
        size_t base = (size_t)(win * 8 + h) * PSTRIDE;
        size_t off = (sec < 2) ? base + (size_t)sec * 3136 + tok * 32 + d
                               : base + 6272 + d * 128 + tok;
        C[off] = (__bf16)acc[m][n][r];
      }
    }
}

// ---------------- attention: zero-LDS/zero-barrier, K & V^T frags hoisted to regs ----------------
__launch_bounds__(128)
__global__ void attn_kernel(const __bf16* __restrict__ qkv, const float* __restrict__ cmb,
                            __bf16* __restrict__ y) {
  int bx = blockIdx.x;
  int lb = (bx & 7) * 2048 + (bx >> 3);        // win-major within each XCD (R8 streaming order)
  const int win = lb >> 3, h = lb & 7;
  const int tid = threadIdx.x;
  const int lane = tid & 63, wv = tid >> 6;
  const int lr = lane & 15, lg = lane >> 4;
  const f32x4 fz = {0.f, 0.f, 0.f, 0.f};

  const __bf16* qw = qkv + (size_t)(win * 8 + h) * PSTRIDE;
  const __bf16* kw = qw + 3136;
  const __bf16* vwT = qw + 6272;               // [32 d][128 tok]
  const float* cw = cmb + (size_t)((win & 255) * 8 + h) * (NTOK * 128);

  // hoist K fragments (i-tile-invariant): permuted rows so P slots == PV A-frag slots
  bf16x8 bk[7];
#pragma unroll
  for (int jt = 0; jt < 7; ++jt) {
    int brow = ((jt >> 1) << 5) + ((lr >> 2) << 3) + ((jt & 1) << 2) + (lr & 3);
    int browc = brow < NTOK ? brow : NTOK - 1;
    bk[jt] = *(const bf16x8*)(kw + browc * 32 + lg * 8);
  }
  // hoist V^T fragments (i-tile-invariant), coalesced
  bf16x8 vb[2][4];
#pragma unroll
  for (int dt = 0; dt < 2; ++dt)
#pragma unroll
    for (int ks = 0; ks < 4; ++ks)
      vb[dt][ks] = *(const bf16x8*)(vwT + (dt * 16 + lr) * 128 + ks * 32 + lg * 8);

  for (int it = wv; it < 7; it += 2) {         // wave0: 0,2,4,6  wave1: 1,3,5
    const int i0 = it * 16;
    const int qrow = i0 + lr;
    const int qrowc = qrow < NTOK ? qrow : NTOK - 1;
    bf16x8 aq = *(const bf16x8*)(qw + qrowc * 32 + lg * 8);

    // prefetch combined bias+mask BEFORE the MFMAs (independent loads hide under QK^T)
    const float* cr = cw + qrowc * 128;
    float4 cv[7];
#pragma unroll
    for (int jt = 0; jt < 7; ++jt) {
      int kb = ((jt >> 1) << 5) + lg * 8 + ((jt & 1) << 2);
      cv[jt] = *(const float4*)(cr + kb);
    }

    // S^T = K Q^T: lane holds P[qrow][k], k = 32*(jt>>1) + lg*8 + 4*(jt&1) + r
    f32x4 s[7];
#pragma unroll
    for (int jt = 0; jt < 7; ++jt)
      s[jt] = __builtin_amdgcn_mfma_f32_16x16x32_bf16(bk[jt], aq, fz, 0, 0, 0);

    // softmax fully in-register (for row qrow = i0 + lr)
    float sv[7][4];
    float mx = -INFINITY;
#pragma unroll
    for (int jt = 0; jt < 7; ++jt) {
      int kb = ((jt >> 1) << 5) + lg * 8 + ((jt & 1) << 2);
#pragma unroll
      for (int r = 0; r < 4; ++r) {
        float xv = (kb + r < NTOK) ? fmaf(SCALE, s[jt][r], (&cv[jt].x)[r]) : -INFINITY;
        sv[jt][r] = xv;
        mx = fmaxf(mx, xv);
      }
    }
    mx = fmaxf(mx, __shfl_xor(mx, 16));
    mx = fmaxf(mx, __shfl_xor(mx, 32));
    float sum = 0.f;
#pragma unroll
    for (int jt = 0; jt < 7; ++jt)
#pragma unroll
      for (int r = 0; r < 4; ++r) {
        float p = __expf(sv[jt][r] - mx);
        sv[jt][r] = p;
        sum += p;
      }
    sum += __shfl_xor(sum, 16);
    sum += __shfl_xor(sum, 32);
    const float rinv = 1.f / sum;   // reciprocal for row i0 + lr (lanes lr,lr+16,lr+32,lr+48 equal)

    // PV A-frags: unnormalized P; normalization applied at the 8 output stores
    bf16x8 pa[4];
#pragma unroll
    for (int ks = 0; ks < 4; ++ks)
#pragma unroll
      for (int e = 0; e < 8; ++e) {
        int jt = 2 * ks + (e >> 2);
        pa[ks][e] = (jt < 7) ? (__bf16)sv[jt][e & 3] : (__bf16)0.f;
      }

    // output row of o[r] is i0 + lg*4 + r -> need rinv from lane (lg*4 + r)
    float rv[4];
#pragma unroll
    for (int r = 0; r < 4; ++r) rv[r] = __shfl(rinv, lg * 4 + r);

    // PV from hoisted V^T frags; y write with row-correct reciprocal
#pragma unroll
    for (int dt = 0; dt < 2; ++dt) {
      f32x4 o = fz;
#pragma unroll
      for (int ks = 0; ks < 4; ++ks)
        o = __builtin_amdgcn_mfma_f32_16x16x32_bf16(pa[ks], vb[dt][ks], o, 0, 0, 0);
#pragma unroll
      for (int r = 0; r < 4; ++r) {
        int row = i0 + lg * 4 + r;
        if (row < NTOK)
          y[((size_t)win * NTOK + row) * 256 + h * 32 + dt * 16 + lr] = (__bf16)(o[r] * rv[r]);
      }
    }
  }
}

// ---------------- proj GEMM: out[M][256] = y[M][256] @ W[256][256]^T + b ----------------
__launch_bounds__(256)
__global__ void gemm_proj(const __bf16* __restrict__ A, const __bf16* __restrict__ W,
                          const float* __restrict__ pb, float* __restrict__ C) {
  __shared__ __align__(16) char As[128 * 128];
  __shared__ __align__(16) char Bs[128 * 128];
  const int bid = blockIdx.x;
  const int m0 = (bid / 2) * 128;
  const int n0 = (bid % 2) * 128;
  const int tid = threadIdx.x;
  const int lane = tid & 63;
  const int wid = tid >> 6;
  const int wm = wid & 1, wn = wid >> 1;
  const int lr = lane & 15;
  const int lg = lane >> 4;
  f32x4 acc[4][4] = {};

  for (int k0 = 0; k0 < 256; k0 += 64) {
#pragma unroll
    for (int it = 0; it < 4; ++it) {
      int c = wid * 4 + it;
      int row = c * 8 + (lane >> 3);
      int src_chunk = (lane & 7) ^ (row & 7);
      g2l16(A + (size_t)(m0 + row) * 256 + k0 + src_chunk * 8, (void*)(As + c * 1024));
      g2l16(W + (size_t)(n0 + row) * 256 + k0 + src_chunk * 8, (void*)(Bs + c * 1024));
    }
    __syncthreads();
#pragma unroll
    for (int kk = 0; kk < 2; ++kk) {
      bf16x8 a[4], b[4];
#pragma unroll
      for (int m = 0; m < 4; ++m) {
        int row = wm * 64 + m * 16 + lr;
        a[m] = *(const bf16x8*)(As + row * 128 + ((kk * 64 + lg * 16) ^ ((row & 7) << 4)));
      }
#pragma unroll
      for (int n = 0; n < 4; ++n) {
        int row = wn * 64 + n * 16 + lr;
        b[n] = *(const bf16x8*)(Bs + row * 128 + ((kk * 64 + lg * 16) ^ ((row & 7) << 4)));
      }
#pragma unroll
      for (int m = 0; m < 4; ++m)
#pragma unroll
        for (int n = 0; n < 4; ++n)
          acc[m][n] = __builtin_amdgcn_mfma_f32_16x16x32_bf16(a[m], b[n], acc[m][n], 0, 0, 0);
    }
    __syncthreads();
  }
#pragma unroll
  for (int m = 0; m < 4; ++m) {
    int row = m0 + wm * 64 + m * 16 + lg * 4;
#pragma unroll
    for (int n = 0; n < 4; ++n) {
      int col = n0 + wn * 64 + n * 16 + lr;
      float bv = pb[col];
#pragma unroll
      for (int r = 0; r < 4; ++r)
        C[(size_t)(row + r) * 256 + col] = acc[m][n][r] + bv;
    }
  }
}

// ---------------- launch ----------------
extern "C" void kernel_launch(void* const* d_in, const int* in_sizes, int n_in,
                              void* d_out, int out_size, void* d_ws, size_t ws_size,
                              hipStream_t stream) {
  const float* x      = (const float*)d_in[0];
  const float* mask   = (const float*)d_in[1];
  const float* pbt    = (const float*)d_in[2];
  const float* qkv_w  = (const float*)d_in[3];
  const float* proj_w = (const float*)d_in[4];
  const float* proj_b = (const float*)d_in[5];
  const int*   rpi    = (const int*)d_in[6];
  float* out = (float*)d_out;

  char* ws = (char*)d_ws;
  __bf16* qkv      = (__bf16*)(ws);                   // 16384*10368*2 = 339,738,624
  __bf16* xb       = (__bf16*)(ws + 339738624);       // 103MB; ALIASES y (xb dead before attn)
  __bf16* y        = (__bf16*)(ws + 339738624);       // 200704*256*2 = 102,760,448
  __bf16* qkvw_b   = (__bf16*)(ws + 442499072);       // 393,216
  __bf16* projw_b  = (__bf16*)(ws + 442892288);       // 131,072
  float*  cmb      = (float*) (ws + 443023360);       // 256*8*98*128*4 = 102,760,448 (~546MB)

  int prep_n = 256 * 8 * NTOK * 128;
  prep_kernel<<<(prep_n + 255) / 256, 256, 0, stream>>>(qkv_w, proj_w, pbt, rpi, mask,
                                                        qkvw_b, projw_b, cmb);
  zpad_kernel<<<8192, 256, 0, stream>>>(qkv);
  xcast_kernel<<<MROWS * 256 / 8 / 256, 256, 0, stream>>>(x, xb);
  gemm_qkv<<<(MROWS / 128) * 6, 256, 0, stream>>>(xb, qkvw_b, qkv);
  attn_kernel<<<NWIN * 8, 128, 0, stream>>>(qkv, cmb, y);
  gemm_proj<<<(MROWS / 128) * 2, 256, 0, stream>>>(y, projw_b, proj_b, out);
}